// Round 2
// baseline (5107.625 us; speedup 1.0000x reference)
//
#include <hip/hip_runtime.h>
#include <hip/hip_bf16.h>

typedef _Float16 f16x8 __attribute__((ext_vector_type(8)));
typedef float f32x4 __attribute__((ext_vector_type(4)));
typedef unsigned int u32;
typedef unsigned long long u64;

// Problem dims
constexpr int kIN = 512;
constexpr int kHID = 1024;
constexpr int kGH = 4096;    // 4*H
constexpr int kT = 512;
constexpr int kB = 32;

// Workspace offsets (bytes)
constexpr size_t OFF_XG   = 0;            // [16384][4096] f16 = 134217728
constexpr size_t OFF_XH   = 134217728;    // [16384][512]  f16 = 16777216
constexpr size_t OFF_WXH  = 150994944;    // [4096][512]   f16 = 4194304
constexpr size_t OFF_WHH  = 155189248;    // [4096][1024]  f16 = 8388608
constexpr size_t OFF_BIAS = 163577856;    // [4096]        f32 = 16384
constexpr size_t OFF_HBUF = 163594240;    // [2][32][512]  u32 = 131072
constexpr size_t OFF_FLAG = 163725312;    // [512][64]     u32 = 131072
constexpr size_t WS_NEED  = 163856384;

__device__ __forceinline__ float sigm_f(float x) {
  x = fminf(fmaxf(x, -30.f), 30.f);
  return 1.f / (1.f + __expf(-x));
}
__device__ __forceinline__ float tanh_f(float x) {
  x = fminf(fmaxf(x, -15.f), 15.f);
  float e = __expf(2.f * x);
  return (e - 1.f) / (e + 1.f);
}

// ---------------------------------------------------------------------------
// K0: convert x/Wx/Wh to fp16, bias = bx+bh, zero sync flags (atomic, sc1).
// ---------------------------------------------------------------------------
__global__ void k0_prep(const float* __restrict__ x, const float* __restrict__ Wx,
                        const float* __restrict__ bx, const float* __restrict__ Wh,
                        const float* __restrict__ bh,
                        _Float16* __restrict__ xh, _Float16* __restrict__ wxh,
                        _Float16* __restrict__ whh, float* __restrict__ bias,
                        u32* __restrict__ flags) {
  const long NX = 8388608, NWX = 2097152, NWH = 4194304, NBI = 4096, NFL = 32768;
  const long total = NX + NWX + NWH + NBI + NFL;
  for (long i = (long)blockIdx.x * blockDim.x + threadIdx.x; i < total;
       i += (long)gridDim.x * blockDim.x) {
    long j = i;
    if (j < NX) { xh[j] = (_Float16)x[j]; continue; }
    j -= NX;
    if (j < NWX) { wxh[j] = (_Float16)Wx[j]; continue; }
    j -= NWX;
    if (j < NWH) { whh[j] = (_Float16)Wh[j]; continue; }
    j -= NWH;
    if (j < NBI) { bias[j] = bx[j] + bh[j]; continue; }
    j -= NBI;
    // zero flags at the coherence point so k2's sc1 loads can never see stale 1s
    __hip_atomic_store(&flags[j], 0u, __ATOMIC_RELAXED, __HIP_MEMORY_SCOPE_AGENT);
  }
}

// ---------------------------------------------------------------------------
// K1: xg[m][g] = sum_k xh[m][k] * wxh[g][k] + bias[g]   (B^T GEMM, fp16 MFMA)
// 128x128 tile, BK=32, 256 threads (4 waves of 64x64). Unchanged from R1
// (validated correct on call #1).
// ---------------------------------------------------------------------------
__global__ __launch_bounds__(256) void k1_xgemm(const _Float16* __restrict__ A,
                                                const _Float16* __restrict__ Bm,
                                                const float* __restrict__ bias,
                                                _Float16* __restrict__ C) {
  __shared__ _Float16 sA[128 * 32];
  __shared__ _Float16 sB[128 * 32];
  const int tid = threadIdx.x;
  const int lane = tid & 63, w = tid >> 6;
  const long m0 = (long)blockIdx.x * 128;
  const long n0 = (long)blockIdx.y * 128;
  const int wm = (w & 1) * 64, wn = (w >> 1) * 64;
  const int fr = lane & 15, fk = (lane >> 4) * 8;

  f32x4 acc[4][4] = {};

  for (int k0 = 0; k0 < kIN; k0 += 32) {
#pragma unroll
    for (int it = 0; it < 2; ++it) {
      int c = it * 256 + tid;
      int row = c >> 2, seg = c & 3;
      *(f16x8*)&sA[c * 8] = *(const f16x8*)&A[(m0 + row) * kIN + k0 + seg * 8];
      *(f16x8*)&sB[c * 8] = *(const f16x8*)&Bm[(n0 + row) * kIN + k0 + seg * 8];
    }
    __syncthreads();
    f16x8 af[4], bf[4];
#pragma unroll
    for (int t = 0; t < 4; ++t) {
      af[t] = *(const f16x8*)&sA[(wm + t * 16 + fr) * 32 + fk];
      bf[t] = *(const f16x8*)&sB[(wn + t * 16 + fr) * 32 + fk];
    }
#pragma unroll
    for (int mt = 0; mt < 4; ++mt)
#pragma unroll
      for (int nt = 0; nt < 4; ++nt)
        acc[mt][nt] = __builtin_amdgcn_mfma_f32_16x16x32_f16(af[mt], bf[nt], acc[mt][nt], 0, 0, 0);
    __syncthreads();
  }

  const int cn = lane & 15, cm4 = (lane >> 4) * 4;
#pragma unroll
  for (int nt = 0; nt < 4; ++nt) {
    long col = n0 + wn + nt * 16 + cn;
    float bv = bias[col];
#pragma unroll
    for (int mt = 0; mt < 4; ++mt)
#pragma unroll
      for (int r = 0; r < 4; ++r) {
        long row = m0 + wm + mt * 16 + cm4 + r;
        C[row * kGH + col] = (_Float16)(acc[mt][nt][r] + bv);
      }
  }
}

// ---------------------------------------------------------------------------
// K2: persistent recurrent kernel. 64 blocks x 256 threads.
// h exchange is WRITE-THROUGH at the coherence point: all hbuf traffic uses
// relaxed agent-scope atomics (sc1 -> bypasses L1/L2, hits LLC). Correctness
// does not depend on fence lowering or on cache state left by prior replays.
// Order: h atomic-stores -> __syncthreads (drains vmcnt: write-through
// complete) -> tid0 release-stores the per-block flag. Readers spin on sc1
// flag loads, then sc1-load h fragments directly from LLC.
// ---------------------------------------------------------------------------
__global__ __launch_bounds__(256, 1) void k2_rec(const _Float16* __restrict__ xg,
                                                 const _Float16* __restrict__ whh,
                                                 u32* __restrict__ hbuf,
                                                 u32* __restrict__ flags,
                                                 float* __restrict__ out) {
  const int tid = threadIdx.x;
  const int lane = tid & 63, w = tid >> 6;
  const int bid = blockIdx.x;    // 0..63
  const int jb = bid * 16;

  __shared__ float part[4 * 64 * 33];  // [wave][n(64)][m pad 33]

  const int fr = lane & 15;
  const int fq = lane >> 4;
  const int wk = w * 256;

  // Preload B-fragments (Wh slice lives in registers for the whole scan)
  f16x8 bfr[4][8];
#pragma unroll
  for (int nt = 0; nt < 4; ++nt) {
    long grow = (long)(nt * kHID + jb + fr) * kHID;
#pragma unroll
    for (int kt = 0; kt < 8; ++kt)
      bfr[nt][kt] = *(const f16x8*)&whh[grow + wk + kt * 32 + fq * 8];
  }

  // Elementwise ownership: (b = tid&31, j = jb + (tid>>5)*2 + {0,1})
  const int eb = tid & 31;
  const int jj0 = (tid >> 5) * 2;  // 0,2,..,14
  float cst0 = 0.f, cst1 = 0.f;

  for (int t = 0; t < kT; ++t) {
    // Prefetch xg for this step (independent of h -> issue before the spin)
    u32 xv[4];
    {
      const u32* xgu = (const u32*)xg;
      long rowbase = ((long)eb * kT + t) * (kGH / 2) + (jb + jj0) / 2;
#pragma unroll
      for (int g = 0; g < 4; ++g) xv[g] = xgu[rowbase + g * (kHID / 2)];
    }

    f32x4 acc[2][4] = {};
    if (t > 0) {
      // Acquire: wave-parallel spin, lane l polls flag of block l (sc1 load).
      u32* fl = flags + (size_t)(t - 1) * 64;
      while (true) {
        u32 f = __hip_atomic_load(&fl[lane], __ATOMIC_RELAXED, __HIP_MEMORY_SCOPE_AGENT);
        if (__all(f != 0)) break;
        __builtin_amdgcn_s_sleep(2);
      }
      asm volatile("" ::: "memory");  // compiler barrier: keep h loads below

      // A-fragments straight from LLC via u64 atomic loads (cache-proof).
      const u64* hp64 = (const u64*)(hbuf + ((t & 1) ^ 1) * (kB * kHID / 2));
      u64 hr[2][8][2];
#pragma unroll
      for (int kt = 0; kt < 8; ++kt) {
        int cidx = w * 64 + kt * 8 + fq * 2;  // u64 index within a 256-u64 row
#pragma unroll
        for (int q = 0; q < 2; ++q) {
          hr[0][kt][q] = __hip_atomic_load(&hp64[(size_t)fr * 256 + cidx + q],
                                           __ATOMIC_RELAXED, __HIP_MEMORY_SCOPE_AGENT);
          hr[1][kt][q] = __hip_atomic_load(&hp64[(size_t)(fr + 16) * 256 + cidx + q],
                                           __ATOMIC_RELAXED, __HIP_MEMORY_SCOPE_AGENT);
        }
      }
#pragma unroll
      for (int kt = 0; kt < 8; ++kt) {
        union { u64 u[2]; f16x8 v; } ua, ub;
        ua.u[0] = hr[0][kt][0]; ua.u[1] = hr[0][kt][1];
        ub.u[0] = hr[1][kt][0]; ub.u[1] = hr[1][kt][1];
#pragma unroll
        for (int nt = 0; nt < 4; ++nt) {
          acc[0][nt] = __builtin_amdgcn_mfma_f32_16x16x32_f16(ua.v, bfr[nt][kt], acc[0][nt], 0, 0, 0);
          acc[1][nt] = __builtin_amdgcn_mfma_f32_16x16x32_f16(ub.v, bfr[nt][kt], acc[1][nt], 0, 0, 0);
        }
      }
    }

    // Store partials: n = nt*16 + fr, m = mt*16 + fq*4 + r
#pragma unroll
    for (int mt = 0; mt < 2; ++mt)
#pragma unroll
      for (int nt = 0; nt < 4; ++nt)
        *(f32x4*)&part[(w * 64 + nt * 16 + fr) * 33 + mt * 16 + fq * 4] = acc[mt][nt];
    __syncthreads();

    // Reduce partials + elementwise LSTM for (eb, jj0) and (eb, jj0+1)
    float g0[4], g1[4];
#pragma unroll
    for (int g = 0; g < 4; ++g) {
      union { u32 u; _Float16 h[2]; } xu;
      xu.u = xv[g];
      float s0 = (float)xu.h[0], s1 = (float)xu.h[1];
      int n0 = g * 16 + jj0;
#pragma unroll
      for (int wv = 0; wv < 4; ++wv) {
        s0 += part[(wv * 64 + n0) * 33 + eb];
        s1 += part[(wv * 64 + n0 + 1) * 33 + eb];
      }
      g0[g] = s0; g1[g] = s1;
    }
    float h0, h1;
    {
      float ig = sigm_f(g0[0]), fg = sigm_f(g0[1]);
      float gg = tanh_f(g0[2]), og = sigm_f(g0[3]);
      cst0 = cst0 * fg + ig * gg;
      h0 = og * tanh_f(cst0);
    }
    {
      float ig = sigm_f(g1[0]), fg = sigm_f(g1[1]);
      float gg = tanh_f(g1[2]), og = sigm_f(g1[3]);
      cst1 = cst1 * fg + ig * gg;
      h1 = og * tanh_f(cst1);
    }

    *(float2*)&out[((long)eb * kT + t) * kHID + jb + jj0] = make_float2(h0, h1);

    // Publish h: packed 2xf16, write-through atomic store.
    union { u32 u; _Float16 h[2]; } pk;
    pk.h[0] = (_Float16)h0; pk.h[1] = (_Float16)h1;
    __hip_atomic_store(&hbuf[(t & 1) * (kB * kHID / 2) + eb * (kHID / 2) + (jb + jj0) / 2],
                       pk.u, __ATOMIC_RELAXED, __HIP_MEMORY_SCOPE_AGENT);

    __syncthreads();  // drains vmcnt in every thread: all h stores at LLC
    if (tid == 0)
      __hip_atomic_store(&flags[(size_t)t * 64 + bid], 1u, __ATOMIC_RELEASE,
                         __HIP_MEMORY_SCOPE_AGENT);
  }
}

// ---------------------------------------------------------------------------
extern "C" void kernel_launch(void* const* d_in, const int* in_sizes, int n_in,
                              void* d_out, int out_size, void* d_ws, size_t ws_size,
                              hipStream_t stream) {
  const float* x  = (const float*)d_in[0];
  const float* Wx = (const float*)d_in[1];
  const float* bx = (const float*)d_in[2];
  const float* Wh = (const float*)d_in[3];
  const float* bh = (const float*)d_in[4];
  float* out = (float*)d_out;

  if (ws_size < WS_NEED) return;

  char* ws = (char*)d_ws;
  _Float16* xg    = (_Float16*)(ws + OFF_XG);
  _Float16* xh    = (_Float16*)(ws + OFF_XH);
  _Float16* wxh   = (_Float16*)(ws + OFF_WXH);
  _Float16* whh   = (_Float16*)(ws + OFF_WHH);
  float*    bias  = (float*)(ws + OFF_BIAS);
  u32*      hbuf  = (u32*)(ws + OFF_HBUF);
  u32*      flags = (u32*)(ws + OFF_FLAG);

  hipLaunchKernelGGL(k0_prep, dim3(4096), dim3(256), 0, stream,
                     x, Wx, bx, Wh, bh, xh, wxh, whh, bias, flags);
  hipLaunchKernelGGL(k1_xgemm, dim3(128, 32), dim3(256), 0, stream,
                     xh, wxh, bias, xg);
  hipLaunchKernelGGL(k2_rec, dim3(64), dim3(256), 0, stream,
                     xg, whh, hbuf, flags, out);
}

// Round 3
// 4289.454 us; speedup vs baseline: 1.1907x; 1.1907x over previous
//
#include <hip/hip_runtime.h>
#include <hip/hip_bf16.h>

typedef _Float16 f16x8 __attribute__((ext_vector_type(8)));
typedef float f32x4 __attribute__((ext_vector_type(4)));
typedef unsigned int u32;
typedef unsigned long long u64;

// Problem dims
constexpr int kIN = 512;
constexpr int kHID = 1024;
constexpr int kGH = 4096;    // 4*H
constexpr int kT = 512;
constexpr int kB = 32;

// Workspace offsets (bytes)
constexpr size_t OFF_XG   = 0;            // [16384][4096] f16 = 134217728
constexpr size_t OFF_XH   = 134217728;    // [16384][512]  f16 = 16777216
constexpr size_t OFF_WXH  = 150994944;    // [4096][512]   f16 = 4194304
constexpr size_t OFF_WHH  = 155189248;    // [4096][1024]  f16 = 8388608
constexpr size_t OFF_BIAS = 163577856;    // [4096]        f32 = 16384
constexpr size_t OFF_HBUF = 163594240;    // [2][32][512]  u32 = 131072
constexpr size_t OFF_CNT  = 163725312;    // [512][16]     u32 = 32768 (64B stride)
constexpr size_t WS_NEED  = 163856384;

__device__ __forceinline__ float sigm_f(float x) {
  x = fminf(fmaxf(x, -30.f), 30.f);
  return 1.f / (1.f + __expf(-x));
}
__device__ __forceinline__ float tanh_f(float x) {
  x = fminf(fmaxf(x, -15.f), 15.f);
  float e = __expf(2.f * x);
  return (e - 1.f) / (e + 1.f);
}

// ---------------------------------------------------------------------------
// K0: convert x/Wx/Wh to fp16, bias = bx+bh, zero step counters (atomic).
// ---------------------------------------------------------------------------
__global__ void k0_prep(const float* __restrict__ x, const float* __restrict__ Wx,
                        const float* __restrict__ bx, const float* __restrict__ Wh,
                        const float* __restrict__ bh,
                        _Float16* __restrict__ xh, _Float16* __restrict__ wxh,
                        _Float16* __restrict__ whh, float* __restrict__ bias,
                        u32* __restrict__ cnt) {
  const long NX = 8388608, NWX = 2097152, NWH = 4194304, NBI = 4096, NFL = 8192;
  const long total = NX + NWX + NWH + NBI + NFL;
  for (long i = (long)blockIdx.x * blockDim.x + threadIdx.x; i < total;
       i += (long)gridDim.x * blockDim.x) {
    long j = i;
    if (j < NX) { xh[j] = (_Float16)x[j]; continue; }
    j -= NX;
    if (j < NWX) { wxh[j] = (_Float16)Wx[j]; continue; }
    j -= NWX;
    if (j < NWH) { whh[j] = (_Float16)Wh[j]; continue; }
    j -= NWH;
    if (j < NBI) { bias[j] = bx[j] + bh[j]; continue; }
    j -= NBI;
    __hip_atomic_store(&cnt[j], 0u, __ATOMIC_RELAXED, __HIP_MEMORY_SCOPE_AGENT);
  }
}

// ---------------------------------------------------------------------------
// K1: xg[m][g] = sum_k xh[m][k] * wxh[g][k] + bias[g]   (B^T GEMM, fp16 MFMA)
// 128x128 tile, BK=32, 256 threads. Validated in R1/R2.
// ---------------------------------------------------------------------------
__global__ __launch_bounds__(256) void k1_xgemm(const _Float16* __restrict__ A,
                                                const _Float16* __restrict__ Bm,
                                                const float* __restrict__ bias,
                                                _Float16* __restrict__ C) {
  __shared__ _Float16 sA[128 * 32];
  __shared__ _Float16 sB[128 * 32];
  const int tid = threadIdx.x;
  const int lane = tid & 63, w = tid >> 6;
  const long m0 = (long)blockIdx.x * 128;
  const long n0 = (long)blockIdx.y * 128;
  const int wm = (w & 1) * 64, wn = (w >> 1) * 64;
  const int fr = lane & 15, fk = (lane >> 4) * 8;

  f32x4 acc[4][4] = {};

  for (int k0 = 0; k0 < kIN; k0 += 32) {
#pragma unroll
    for (int it = 0; it < 2; ++it) {
      int c = it * 256 + tid;
      int row = c >> 2, seg = c & 3;
      *(f16x8*)&sA[c * 8] = *(const f16x8*)&A[(m0 + row) * kIN + k0 + seg * 8];
      *(f16x8*)&sB[c * 8] = *(const f16x8*)&Bm[(n0 + row) * kIN + k0 + seg * 8];
    }
    __syncthreads();
    f16x8 af[4], bf[4];
#pragma unroll
    for (int t = 0; t < 4; ++t) {
      af[t] = *(const f16x8*)&sA[(wm + t * 16 + fr) * 32 + fk];
      bf[t] = *(const f16x8*)&sB[(wn + t * 16 + fr) * 32 + fk];
    }
#pragma unroll
    for (int mt = 0; mt < 4; ++mt)
#pragma unroll
      for (int nt = 0; nt < 4; ++nt)
        acc[mt][nt] = __builtin_amdgcn_mfma_f32_16x16x32_f16(af[mt], bf[nt], acc[mt][nt], 0, 0, 0);
    __syncthreads();
  }

  const int cn = lane & 15, cm4 = (lane >> 4) * 4;
#pragma unroll
  for (int nt = 0; nt < 4; ++nt) {
    long col = n0 + wn + nt * 16 + cn;
    float bv = bias[col];
#pragma unroll
    for (int mt = 0; mt < 4; ++mt)
#pragma unroll
      for (int r = 0; r < 4; ++r) {
        long row = m0 + wm + mt * 16 + cm4 + r;
        C[row * kGH + col] = (_Float16)(acc[mt][nt][r] + bv);
      }
  }
}

// ---------------------------------------------------------------------------
// K2: persistent recurrent kernel. 64 blocks x 256 threads.
// Sync per step: each block does ONE atomicAdd on a 64B-padded counter;
// only wave0 polls it (one coalesced same-address load per round); the
// last-arriving block skips the poll (its add returned 63). h exchange is
// write-through agent-scope atomics (LLC, cache-proof across replays).
// ---------------------------------------------------------------------------
__global__ __launch_bounds__(256, 1) void k2_rec(const _Float16* __restrict__ xg,
                                                 const _Float16* __restrict__ whh,
                                                 u32* __restrict__ hbuf,
                                                 u32* __restrict__ cnt,
                                                 float* __restrict__ out) {
  const int tid = threadIdx.x;
  const int lane = tid & 63, w = tid >> 6;
  const int bid = blockIdx.x;    // 0..63
  const int jb = bid * 16;

  __shared__ float part[4 * 64 * 35];  // [wave][n(64)][m pad 35]

  const int fr = lane & 15;
  const int fq = lane >> 4;

  // Preload B-fragments (Wh slice stays in registers for the whole scan)
  f16x8 bfr[4][8];
#pragma unroll
  for (int nt = 0; nt < 4; ++nt) {
    long grow = (long)(nt * kHID + jb + fr) * kHID;
#pragma unroll
    for (int kt = 0; kt < 8; ++kt)
      bfr[nt][kt] = *(const f16x8*)&whh[grow + w * 256 + kt * 32 + fq * 8];
  }

  // Elementwise ownership: b = tid>>3 (0..31), jpair = tid&7 -> j = jb + jpair*2 + {0,1}
  const int eb = tid >> 3;
  const int jp = tid & 7;
  float cst0 = 0.f, cst1 = 0.f;
  bool last = false;

  for (int t = 0; t < kT; ++t) {
    // Prefetch xg for this step (independent of h -> in flight during the spin).
    // 8 lanes with the same b share a line per gate -> coalesces to 1 request.
    u32 xv[4];
    {
      const u32* xgu = (const u32*)xg;
      long rowbase = ((long)eb * kT + t) * (kGH / 2) + bid * 8 + jp;
#pragma unroll
      for (int g = 0; g < 4; ++g) xv[g] = xgu[rowbase + g * (kHID / 2)];
    }

    if (t > 0) {
      if (w == 0 && !last) {
        const u32* cp = &cnt[(size_t)(t - 1) * 16];
        while (__hip_atomic_load(cp, __ATOMIC_RELAXED, __HIP_MEMORY_SCOPE_AGENT) < 64u) {
        }
      }
    }
    __syncthreads();  // releases waves 1-3 once wave0 has seen count==64

    f32x4 acc[2][4] = {};
    if (t > 0) {
      // A-fragments straight from LLC via u64 atomic loads (cache-proof).
      const u64* hp64 = (const u64*)(hbuf + ((t & 1) ^ 1) * (kB * kHID / 2));
      u64 hr[2][8][2];
#pragma unroll
      for (int kt = 0; kt < 8; ++kt) {
        int cidx = w * 64 + kt * 8 + fq * 2;
#pragma unroll
        for (int q = 0; q < 2; ++q) {
          hr[0][kt][q] = __hip_atomic_load(&hp64[(size_t)fr * 256 + cidx + q],
                                           __ATOMIC_RELAXED, __HIP_MEMORY_SCOPE_AGENT);
          hr[1][kt][q] = __hip_atomic_load(&hp64[(size_t)(fr + 16) * 256 + cidx + q],
                                           __ATOMIC_RELAXED, __HIP_MEMORY_SCOPE_AGENT);
        }
      }
#pragma unroll
      for (int kt = 0; kt < 8; ++kt) {
        union { u64 u[2]; f16x8 v; } ua, ub;
        ua.u[0] = hr[0][kt][0]; ua.u[1] = hr[0][kt][1];
        ub.u[0] = hr[1][kt][0]; ub.u[1] = hr[1][kt][1];
#pragma unroll
        for (int nt = 0; nt < 4; ++nt) {
          acc[0][nt] = __builtin_amdgcn_mfma_f32_16x16x32_f16(ua.v, bfr[nt][kt], acc[0][nt], 0, 0, 0);
          acc[1][nt] = __builtin_amdgcn_mfma_f32_16x16x32_f16(ub.v, bfr[nt][kt], acc[1][nt], 0, 0, 0);
        }
      }
    }

    // Store partials: n = nt*16 + fr, m = mt*16 + fq*4 + r
#pragma unroll
    for (int mt = 0; mt < 2; ++mt)
#pragma unroll
      for (int nt = 0; nt < 4; ++nt)
        *(f32x4*)&part[(w * 64 + nt * 16 + fr) * 35 + mt * 16 + fq * 4] = acc[mt][nt];
    __syncthreads();

    // Reduce partials + elementwise LSTM for (eb, jp*2) and (eb, jp*2+1)
    float g0[4], g1[4];
#pragma unroll
    for (int g = 0; g < 4; ++g) {
      union { u32 u; _Float16 h[2]; } xu;
      xu.u = xv[g];
      float s0 = (float)xu.h[0], s1 = (float)xu.h[1];
      int n0 = g * 16 + jp * 2;
#pragma unroll
      for (int wv = 0; wv < 4; ++wv) {
        s0 += part[(wv * 64 + n0) * 35 + eb];
        s1 += part[(wv * 64 + n0 + 1) * 35 + eb];
      }
      g0[g] = s0; g1[g] = s1;
    }
    float h0, h1;
    {
      float ig = sigm_f(g0[0]), fg = sigm_f(g0[1]);
      float gg = tanh_f(g0[2]), og = sigm_f(g0[3]);
      cst0 = cst0 * fg + ig * gg;
      h0 = og * tanh_f(cst0);
    }
    {
      float ig = sigm_f(g1[0]), fg = sigm_f(g1[1]);
      float gg = tanh_f(g1[2]), og = sigm_f(g1[3]);
      cst1 = cst1 * fg + ig * gg;
      h1 = og * tanh_f(cst1);
    }

    // Publish h: packed 2xf16, write-through atomic store (32B/row chunks).
    union { u32 u; _Float16 h[2]; } pk;
    pk.h[0] = (_Float16)h0; pk.h[1] = (_Float16)h1;
    __hip_atomic_store(&hbuf[(t & 1) * (kB * kHID / 2) + eb * (kHID / 2) + bid * 8 + jp],
                       pk.u, __ATOMIC_RELAXED, __HIP_MEMORY_SCOPE_AGENT);

    __syncthreads();  // drains vmcnt in every thread: all h stores at LLC

    u32 old = 0;
    if (tid == 0)
      old = __hip_atomic_fetch_add(&cnt[(size_t)t * 16], 1u, __ATOMIC_RELEASE,
                                   __HIP_MEMORY_SCOPE_AGENT);
    last = (__builtin_amdgcn_readfirstlane(old) == 63u);  // valid in wave0 only

    // out store AFTER the release: its completion is off the critical path.
    // Full 64B lines per b-row (16 consecutive floats per block).
    *(float2*)&out[((long)eb * kT + t) * kHID + jb + jp * 2] = make_float2(h0, h1);
  }
}

// ---------------------------------------------------------------------------
extern "C" void kernel_launch(void* const* d_in, const int* in_sizes, int n_in,
                              void* d_out, int out_size, void* d_ws, size_t ws_size,
                              hipStream_t stream) {
  const float* x  = (const float*)d_in[0];
  const float* Wx = (const float*)d_in[1];
  const float* bx = (const float*)d_in[2];
  const float* Wh = (const float*)d_in[3];
  const float* bh = (const float*)d_in[4];
  float* out = (float*)d_out;

  if (ws_size < WS_NEED) return;

  char* ws = (char*)d_ws;
  _Float16* xg    = (_Float16*)(ws + OFF_XG);
  _Float16* xh    = (_Float16*)(ws + OFF_XH);
  _Float16* wxh   = (_Float16*)(ws + OFF_WXH);
  _Float16* whh   = (_Float16*)(ws + OFF_WHH);
  float*    bias  = (float*)(ws + OFF_BIAS);
  u32*      hbuf  = (u32*)(ws + OFF_HBUF);
  u32*      cnt   = (u32*)(ws + OFF_CNT);

  hipLaunchKernelGGL(k0_prep, dim3(4096), dim3(256), 0, stream,
                     x, Wx, bx, Wh, bh, xh, wxh, whh, bias, cnt);
  hipLaunchKernelGGL(k1_xgemm, dim3(128, 32), dim3(256), 0, stream,
                     xh, wxh, bias, xg);
  hipLaunchKernelGGL(k2_rec, dim3(64), dim3(256), 0, stream,
                     xg, whh, hbuf, cnt, out);
}

// Round 4
// 3922.723 us; speedup vs baseline: 1.3021x; 1.0935x over previous
//
#include <hip/hip_runtime.h>
#include <hip/hip_bf16.h>

typedef _Float16 f16x8 __attribute__((ext_vector_type(8)));
typedef float f32x4 __attribute__((ext_vector_type(4)));
typedef unsigned int u32;
typedef unsigned long long u64;

// Problem dims
constexpr int kIN = 512;
constexpr int kHID = 1024;
constexpr int kGH = 4096;    // 4*H
constexpr int kT = 512;
constexpr int kB = 32;

constexpr u32 SENT32 = 0x7FFF7FFFu;  // f16 NaN pair; |h|<=1 can never encode this

// Workspace offsets (bytes)
constexpr size_t OFF_XG    = 0;            // [16384][4096] f16 = 134217728
constexpr size_t OFF_XH    = 134217728;    // [16384][512]  f16 = 16777216
constexpr size_t OFF_WXH   = 150994944;    // [4096][512]   f16 = 4194304
constexpr size_t OFF_WHH   = 155189248;    // [4096][1024]  f16 = 8388608
constexpr size_t OFF_BIAS  = 163577856;    // [4096]        f32 = 16384
constexpr size_t OFF_HRING = 163594240;    // [4][32][512]  u32 = 262144 (4-slot ring)
constexpr size_t WS_NEED   = 163856384;    // same as R3 (proven available)

__device__ __forceinline__ float sigm_f(float x) {
  x = fminf(fmaxf(x, -30.f), 30.f);
  return 1.f / (1.f + __expf(-x));
}
__device__ __forceinline__ float tanh_f(float x) {
  x = fminf(fmaxf(x, -15.f), 15.f);
  float e = __expf(2.f * x);
  return (e - 1.f) / (e + 1.f);
}

// ---------------------------------------------------------------------------
// K0: convert x/Wx/Wh to fp16, bias = bx+bh, sentinel-fill the h ring.
// ---------------------------------------------------------------------------
__global__ void k0_prep(const float* __restrict__ x, const float* __restrict__ Wx,
                        const float* __restrict__ bx, const float* __restrict__ Wh,
                        const float* __restrict__ bh,
                        _Float16* __restrict__ xh, _Float16* __restrict__ wxh,
                        _Float16* __restrict__ whh, float* __restrict__ bias,
                        u32* __restrict__ hring) {
  const long NX = 8388608, NWX = 2097152, NWH = 4194304, NBI = 4096, NRG = 65536;
  const long total = NX + NWX + NWH + NBI + NRG;
  for (long i = (long)blockIdx.x * blockDim.x + threadIdx.x; i < total;
       i += (long)gridDim.x * blockDim.x) {
    long j = i;
    if (j < NX) { xh[j] = (_Float16)x[j]; continue; }
    j -= NX;
    if (j < NWX) { wxh[j] = (_Float16)Wx[j]; continue; }
    j -= NWX;
    if (j < NWH) { whh[j] = (_Float16)Wh[j]; continue; }
    j -= NWH;
    if (j < NBI) { bias[j] = bx[j] + bh[j]; continue; }
    j -= NBI;
    // sentinel-fill at the coherence point (k2 reads via agent-scope loads)
    __hip_atomic_store(&hring[j], SENT32, __ATOMIC_RELAXED, __HIP_MEMORY_SCOPE_AGENT);
  }
}

// ---------------------------------------------------------------------------
// K1: xg[m][g] = sum_k xh[m][k] * wxh[g][k] + bias[g]   (B^T GEMM, fp16 MFMA)
// 128x128 tile, BK=32, 256 threads. Validated in R1-R3.
// ---------------------------------------------------------------------------
__global__ __launch_bounds__(256) void k1_xgemm(const _Float16* __restrict__ A,
                                                const _Float16* __restrict__ Bm,
                                                const float* __restrict__ bias,
                                                _Float16* __restrict__ C) {
  __shared__ _Float16 sA[128 * 32];
  __shared__ _Float16 sB[128 * 32];
  const int tid = threadIdx.x;
  const int lane = tid & 63, w = tid >> 6;
  const long m0 = (long)blockIdx.x * 128;
  const long n0 = (long)blockIdx.y * 128;
  const int wm = (w & 1) * 64, wn = (w >> 1) * 64;
  const int fr = lane & 15, fk = (lane >> 4) * 8;

  f32x4 acc[4][4] = {};

  for (int k0 = 0; k0 < kIN; k0 += 32) {
#pragma unroll
    for (int it = 0; it < 2; ++it) {
      int c = it * 256 + tid;
      int row = c >> 2, seg = c & 3;
      *(f16x8*)&sA[c * 8] = *(const f16x8*)&A[(m0 + row) * kIN + k0 + seg * 8];
      *(f16x8*)&sB[c * 8] = *(const f16x8*)&Bm[(n0 + row) * kIN + k0 + seg * 8];
    }
    __syncthreads();
    f16x8 af[4], bf[4];
#pragma unroll
    for (int t = 0; t < 4; ++t) {
      af[t] = *(const f16x8*)&sA[(wm + t * 16 + fr) * 32 + fk];
      bf[t] = *(const f16x8*)&sB[(wn + t * 16 + fr) * 32 + fk];
    }
#pragma unroll
    for (int mt = 0; mt < 4; ++mt)
#pragma unroll
      for (int nt = 0; nt < 4; ++nt)
        acc[mt][nt] = __builtin_amdgcn_mfma_f32_16x16x32_f16(af[mt], bf[nt], acc[mt][nt], 0, 0, 0);
    __syncthreads();
  }

  const int cn = lane & 15, cm4 = (lane >> 4) * 4;
#pragma unroll
  for (int nt = 0; nt < 4; ++nt) {
    long col = n0 + wn + nt * 16 + cn;
    float bv = bias[col];
#pragma unroll
    for (int mt = 0; mt < 4; ++mt)
#pragma unroll
      for (int r = 0; r < 4; ++r) {
        long row = m0 + wm + mt * 16 + cm4 + r;
        C[row * kGH + col] = (_Float16)(acc[mt][nt][r] + bv);
      }
  }
}

// ---------------------------------------------------------------------------
// K2: persistent recurrent kernel, FLAGLESS sentinel sync. 64 blocks x 256 thr.
// Ring of 4 h-slots (64KB each). Per step t a block:
//   - resets ITS OWN chunk of slot (t+1)&3 to sentinel (top of step),
//   - polls/loads ALL chunks of slot (t-1)&3 until no lane sees sentinel,
//   - computes gates via register-resident Wh MFMA + LDS reduce + elementwise,
//   - s_waitcnt vmcnt(0) (drains ops issued a step ago: ~free), then publishes
//     h into slot t&3 with relaxed agent-scope stores - NO flag, NO drain wait.
// Safety: ring depth 4 covers the 1-step drift bound (a reader accepts slot
// t-1 only when all 64 chunks are fresh => all blocks passed publish(t-1));
// reset->publish same-address coherence prevents stale acceptance.
// ---------------------------------------------------------------------------
__global__ __launch_bounds__(256, 1) void k2_rec(const _Float16* __restrict__ xg,
                                                 const _Float16* __restrict__ whh,
                                                 u32* __restrict__ hring,
                                                 float* __restrict__ out) {
  const int tid = threadIdx.x;
  const int lane = tid & 63, w = tid >> 6;
  const int bid = blockIdx.x;    // 0..63
  const int jb = bid * 16;

  __shared__ float part[4 * 64 * 35];  // [wave][n(64)][m pad 35]

  const int fr = lane & 15;
  const int fq = lane >> 4;

  // Preload B-fragments (Wh slice stays register/AGPR-resident for the scan)
  f16x8 bfr[4][8];
#pragma unroll
  for (int nt = 0; nt < 4; ++nt) {
    long grow = (long)(nt * kHID + jb + fr) * kHID;
#pragma unroll
    for (int kt = 0; kt < 8; ++kt)
      bfr[nt][kt] = *(const f16x8*)&whh[grow + w * 256 + kt * 32 + fq * 8];
  }

  // Elementwise ownership: b = tid>>3 (0..31), jp = tid&7 -> j = jb + jp*2 + {0,1}
  const int eb = tid >> 3;
  const int jp = tid & 7;
  float cst0 = 0.f, cst1 = 0.f;

  for (int t = 0; t < kT; ++t) {
    const int wslot = t & 3, rslot = (t - 1) & 3, zslot = (t + 1) & 3;

    // Reset own chunk of slot (t+1)&3 to sentinel (readers of its old data
    // finished at step t-2; see header proof). Issued early -> lands long
    // before the pre-publish vmcnt drain makes it ordered vs publish(t+1).
    __hip_atomic_store(&hring[zslot * 16384 + eb * 512 + bid * 8 + jp], SENT32,
                       __ATOMIC_RELAXED, __HIP_MEMORY_SCOPE_AGENT);

    // Prefetch xg for this step (independent of h -> in flight during poll)
    u32 xv[4];
    {
      const u32* xgu = (const u32*)xg;
      long rowbase = ((long)eb * kT + t) * (kGH / 2) + bid * 8 + jp;
#pragma unroll
      for (int g = 0; g < 4; ++g) xv[g] = xgu[rowbase + g * (kHID / 2)];
    }

    f32x4 acc[2][4] = {};
    if (t > 0) {
      // Acquire: poll the h data itself; fresh data self-announces (non-NaN).
      const u64* hp64 = (const u64*)(hring + rslot * 16384);
      u64 hr[2][8][2];
      while (true) {
#pragma unroll
        for (int kt = 0; kt < 8; ++kt) {
          int cidx = w * 64 + kt * 8 + fq * 2;
#pragma unroll
          for (int q = 0; q < 2; ++q) {
            hr[0][kt][q] = __hip_atomic_load(&hp64[(size_t)fr * 256 + cidx + q],
                                             __ATOMIC_RELAXED, __HIP_MEMORY_SCOPE_AGENT);
            hr[1][kt][q] = __hip_atomic_load(&hp64[(size_t)(fr + 16) * 256 + cidx + q],
                                             __ATOMIC_RELAXED, __HIP_MEMORY_SCOPE_AGENT);
          }
        }
        u32 bad = 0;
#pragma unroll
        for (int m = 0; m < 2; ++m)
#pragma unroll
          for (int kt = 0; kt < 8; ++kt)
#pragma unroll
            for (int q = 0; q < 2; ++q) {
              u64 v = hr[m][kt][q];
              bad |= ((u32)v == SENT32) | ((u32)(v >> 32) == SENT32);
            }
        if (!__any(bad)) break;
        __builtin_amdgcn_s_sleep(1);
        asm volatile("" ::: "memory");
      }
#pragma unroll
      for (int kt = 0; kt < 8; ++kt) {
        union { u64 u[2]; f16x8 v; } ua, ub;
        ua.u[0] = hr[0][kt][0]; ua.u[1] = hr[0][kt][1];
        ub.u[0] = hr[1][kt][0]; ub.u[1] = hr[1][kt][1];
#pragma unroll
        for (int nt = 0; nt < 4; ++nt) {
          acc[0][nt] = __builtin_amdgcn_mfma_f32_16x16x32_f16(ua.v, bfr[nt][kt], acc[0][nt], 0, 0, 0);
          acc[1][nt] = __builtin_amdgcn_mfma_f32_16x16x32_f16(ub.v, bfr[nt][kt], acc[1][nt], 0, 0, 0);
        }
      }
    }

    // Store partials: n = nt*16 + fr, m = mt*16 + fq*4 + r
#pragma unroll
    for (int mt = 0; mt < 2; ++mt)
#pragma unroll
      for (int nt = 0; nt < 4; ++nt)
        *(f32x4*)&part[(w * 64 + nt * 16 + fr) * 35 + mt * 16 + fq * 4] = acc[mt][nt];
    __syncthreads();

    // Reduce partials + elementwise LSTM for (eb, jp*2) and (eb, jp*2+1)
    float g0[4], g1[4];
#pragma unroll
    for (int g = 0; g < 4; ++g) {
      union { u32 u; _Float16 h[2]; } xu;
      xu.u = xv[g];
      float s0 = (float)xu.h[0], s1 = (float)xu.h[1];
      int n0 = g * 16 + jp * 2;
#pragma unroll
      for (int wv = 0; wv < 4; ++wv) {
        s0 += part[(wv * 64 + n0) * 35 + eb];
        s1 += part[(wv * 64 + n0 + 1) * 35 + eb];
      }
      g0[g] = s0; g1[g] = s1;
    }
    __syncthreads();  // all waves done reading `part` before next step's stores

    float h0, h1;
    {
      float ig = sigm_f(g0[0]), fg = sigm_f(g0[1]);
      float gg = tanh_f(g0[2]), og = sigm_f(g0[3]);
      cst0 = cst0 * fg + ig * gg;
      h0 = og * tanh_f(cst0);
    }
    {
      float ig = sigm_f(g1[0]), fg = sigm_f(g1[1]);
      float gg = tanh_f(g1[2]), og = sigm_f(g1[3]);
      cst1 = cst1 * fg + ig * gg;
      h1 = og * tanh_f(cst1);
    }

    // Order reset(t, slot z) before publish(t): both are vmem stores from this
    // wave; drain is ~free (everything outstanding was issued ~a step ago).
    asm volatile("s_waitcnt vmcnt(0)" ::: "memory");

    // Publish h into slot t&3: relaxed agent-scope store, NO flag, NO wait.
    union { u32 u; _Float16 h[2]; } pk;
    pk.h[0] = (_Float16)h0; pk.h[1] = (_Float16)h1;
    __hip_atomic_store(&hring[wslot * 16384 + eb * 512 + bid * 8 + jp],
                       pk.u, __ATOMIC_RELAXED, __HIP_MEMORY_SCOPE_AGENT);

    // out store after publish: completion off the critical path.
    *(float2*)&out[((long)eb * kT + t) * kHID + jb + jp * 2] = make_float2(h0, h1);
  }
}

// ---------------------------------------------------------------------------
extern "C" void kernel_launch(void* const* d_in, const int* in_sizes, int n_in,
                              void* d_out, int out_size, void* d_ws, size_t ws_size,
                              hipStream_t stream) {
  const float* x  = (const float*)d_in[0];
  const float* Wx = (const float*)d_in[1];
  const float* bx = (const float*)d_in[2];
  const float* Wh = (const float*)d_in[3];
  const float* bh = (const float*)d_in[4];
  float* out = (float*)d_out;

  if (ws_size < WS_NEED) return;

  char* ws = (char*)d_ws;
  _Float16* xg    = (_Float16*)(ws + OFF_XG);
  _Float16* xh    = (_Float16*)(ws + OFF_XH);
  _Float16* wxh   = (_Float16*)(ws + OFF_WXH);
  _Float16* whh   = (_Float16*)(ws + OFF_WHH);
  float*    bias  = (float*)(ws + OFF_BIAS);
  u32*      hring = (u32*)(ws + OFF_HRING);

  hipLaunchKernelGGL(k0_prep, dim3(4096), dim3(256), 0, stream,
                     x, Wx, bx, Wh, bh, xh, wxh, whh, bias, hring);
  hipLaunchKernelGGL(k1_xgemm, dim3(128, 32), dim3(256), 0, stream,
                     xh, wxh, bias, xg);
  hipLaunchKernelGGL(k2_rec, dim3(64), dim3(256), 0, stream,
                     xg, whh, hring, out);
}